// Round 4
// baseline (102.472 us; speedup 1.0000x reference)
//
#include <hip/hip_runtime.h>

// LinearConv2D fused, v4: bf16 MFMA, direct-global fragments, no LDS main loop.
// x[8,128,32,1024] f32, weight[128,16,32,16] f32 -> out[8,128,17,257] f32
// y[n,t] = sum_{f in {2fo-1,2fo}} sum_{d,w} x[b,g16+d,f,4t+w-8]*wt[g16+n,d,f,w]
// GEMM view per (b,g,f): S[n,t] = W[n, k] * Xw[k, t], k = (d,w).
// k-slice of 32 = one d-pair x 16 w  ->  mfma_f32_16x16x32_bf16.
// B-frag: lane holds Xw[k=8q+j, t=16T+c] = x[.., 4t + w - 8] with w=8(q&1)+j
//   -> 8 CONTIGUOUS floats starting tau0 = 64T + 4c + 8(q&1) - 8 (2 dwordx4).
// A-frag: lane holds W[n=c, k=8q+j] = wt[g16+c, 2dp+(q>>1), f, 8(q&1)+j]
//   -> 8 contiguous floats (2 dwordx4), preloaded per f (8 d-pairs, 32 VGPR).
// D-frag: lane holds S[n=4q+r, t=16T+c]  (m89-verified C/D layout).
// Block (b,g,fo) x 256 threads; wave wid owns t-tiles T = 4*wid + tt.
// t=256 edge column: fp32 epilogue (direct global + shfl reduce).

typedef __attribute__((ext_vector_type(8))) short short8v;
typedef __attribute__((ext_vector_type(4))) float f32x4;

#define TPB 256

static __device__ __forceinline__ short f2bf(float f) {   // RNE f32->bf16
    unsigned u = __builtin_bit_cast(unsigned, f);
    u += 0x7FFFu + ((u >> 16) & 1u);
    return (short)(u >> 16);
}

__global__ __launch_bounds__(TPB, 4) void lconv4(
    const float* __restrict__ x,   // [8,128,32,1024]
    const float* __restrict__ wt,  // [128,16,32,16]
    float* __restrict__ out)       // [8,128,17,257]
{
    __shared__ float red[4][16];

    const int fo = blockIdx.x, g = blockIdx.y, b = blockIdx.z;
    const int tid  = threadIdx.x;
    const int lane = tid & 63;
    const int wid  = __builtin_amdgcn_readfirstlane(tid >> 6);
    const int cc = lane & 15;          // fragment column (t or n)
    const int q  = lane >> 4;          // k-group 0..3

    int fvals[2]; int nf = 0;
    if (2*fo - 1 >= 0) fvals[nf++] = 2*fo - 1;
    if (2*fo < 32)     fvals[nf++] = 2*fo;

    const int BG = b*128 + g*16;
    const int tauc = 4*cc + 8*(q&1) - 8;                    // per-lane tau offset
    const int d0r  = (q>>1)*32768;                          // d-within-pair row offset
    const int wlc  = (g*16 + cc)*8192 + (q>>1)*512 + 8*(q&1);

    f32x4 acc[4];
    #pragma unroll
    for (int t = 0; t < 4; ++t) acc[t] = (f32x4){0.f, 0.f, 0.f, 0.f};

    for (int s = 0; s < nf; ++s) {
        const int f = fvals[s];
        const size_t xb = ((size_t)(BG*32) + f) * 1024;

        // ---- A-frags for this f: 8 d-pairs ----
        short8v afr[8];
        #pragma unroll
        for (int dp = 0; dp < 8; ++dp) {
            const float* wp = wt + wlc + dp*1024 + f*16;
            const float4 w0 = *(const float4*)wp;
            const float4 w1 = *(const float4*)(wp + 4);
            union { short8v s8; short h[8]; } u;
            u.h[0]=f2bf(w0.x); u.h[1]=f2bf(w0.y); u.h[2]=f2bf(w0.z); u.h[3]=f2bf(w0.w);
            u.h[4]=f2bf(w1.x); u.h[5]=f2bf(w1.y); u.h[6]=f2bf(w1.z); u.h[7]=f2bf(w1.w);
            afr[dp] = u.s8;
        }

        // ---- main MFMA sweep ----
        #pragma unroll
        for (int dp = 0; dp < 8; ++dp) {
            const float* rb = x + xb + dp*65536 + d0r;      // this lane's d-row
            #pragma unroll
            for (int tt = 0; tt < 4; ++tt) {
                const int T = wid*4 + tt;
                const int tau0 = T*64 + tauc;
                float v[8];
                if (T == 0 || T == 15) {                    // wave-uniform edge path
                    #pragma unroll
                    for (int j = 0; j < 8; ++j) {
                        const int tau = tau0 + j;
                        const int tcl = tau < 0 ? 0 : (tau > 1023 ? 1023 : tau);
                        const float vv = rb[tcl];           // always in-bounds
                        v[j] = (tau == tcl) ? vv : 0.f;     // zero the pad taps
                    }
                } else {
                    const float4 a0 = *(const float4*)(rb + tau0);
                    const float4 a1 = *(const float4*)(rb + tau0 + 4);
                    v[0]=a0.x; v[1]=a0.y; v[2]=a0.z; v[3]=a0.w;
                    v[4]=a1.x; v[5]=a1.y; v[6]=a1.z; v[7]=a1.w;
                }
                union { short8v s8; short h[8]; } ub;
                #pragma unroll
                for (int j = 0; j < 8; ++j) ub.h[j] = f2bf(v[j]);
                acc[tt] = __builtin_amdgcn_mfma_f32_16x16x32_bf16(
                              afr[dp], ub.s8, acc[tt], 0, 0, 0);
            }
        }
    }

    // ---- store t = 0..255 ----
    #pragma unroll
    for (int tt = 0; tt < 4; ++tt) {
        const int t = (wid*4 + tt)*16 + cc;
        #pragma unroll
        for (int r = 0; r < 4; ++r) {
            const int n = q*4 + r;
            float v = acc[tt][r];
            v = (v > 0.f) ? v : 0.01f*v;
            out[(size_t)(BG + n)*4369 + (size_t)fo*257 + t] = v;
        }
    }

    // ---- t = 256 edge column, fp32 (window taps w=0..7 only) ----
    {
        const int n = tid & 15;
        const int d = tid >> 4;
        const size_t xrow_bg = (size_t)BG * 32768;
        float p = 0.f;
        for (int s = 0; s < nf; ++s) {
            const int f = fvals[s];
            const float* xr = x + xrow_bg + (size_t)d*32768 + (size_t)f*1024 + 1016;
            const float* wr = wt + (size_t)(g*16 + n)*8192 + (size_t)d*512 + f*16;
            #pragma unroll
            for (int w = 0; w < 8; ++w) p = fmaf(xr[w], wr[w], p);
        }
        p += __shfl_xor(p, 16);
        p += __shfl_xor(p, 32);
        if (lane < 16) red[wid][lane] = p;
        __syncthreads();
        if (tid < 16) {
            float v = red[0][tid] + red[1][tid] + red[2][tid] + red[3][tid];
            v = (v > 0.f) ? v : 0.01f*v;
            out[(size_t)(BG + tid)*4369 + (size_t)fo*257 + 256] = v;
        }
    }
}

extern "C" void kernel_launch(void* const* d_in, const int* in_sizes, int n_in,
                              void* d_out, int out_size, void* d_ws, size_t ws_size,
                              hipStream_t stream) {
    const float* x  = (const float*)d_in[0];
    const float* wt = (const float*)d_in[1];
    float* out      = (float*)d_out;
    dim3 grid(17, 8, 8);   // (fo, g, b)
    lconv4<<<grid, TPB, 0, stream>>>(x, wt, out);
}

// Round 5
// 53.204 us; speedup vs baseline: 1.9260x; 1.9260x over previous
//
#include <hip/hip_runtime.h>

// LinearConv2D fused v5: bf16 MFMA + pipelined global_load_lds staging.
// x[8,128,32,1024] f32, weight[128,16,32,16] f32 -> out[8,128,17,257] f32
// y[n,t] = sum_{f in {2fo-1,2fo}} sum_{d,w} x[b,g16+d,f,4t+w-8]*wt[g16+n,d,f,w]
// GEMM per (b,g,f): S[n,t] = W[n,k]*Xw[k,t], k=(d,w); k-slice 32 = d-pair x 16w
// -> mfma_f32_16x16x32_bf16 (fragment maps verified by v4 pass).
// LDS: 4 slots x 1040 floats (8-float zero pads both ends; slot = buf*2 + d-in-pair).
// Stage d-pair (q+1) while computing pair q; barrier per step (m97 2-phase).
// B-frag = 2 ds_read_b128 (quarter-wave reads 256B contiguous -> conflict-free).
// Epilogue: per-wave LDS transpose -> contiguous 256B row stores.
// t=256 edge column: fp32 direct-global epilogue.

typedef __attribute__((ext_vector_type(8))) short short8v;
typedef __attribute__((ext_vector_type(4))) float f32x4;

#define TPB 256

static __device__ __forceinline__ short f2bf(float f) {   // RNE f32->bf16
    unsigned u = __builtin_bit_cast(unsigned, f);
    u += 0x7FFFu + ((u >> 16) & 1u);
    return (short)(u >> 16);
}

__global__ __launch_bounds__(TPB, 4) void lconv5(
    const float* __restrict__ x,   // [8,128,32,1024]
    const float* __restrict__ wt,  // [128,16,32,16]
    float* __restrict__ out)       // [8,128,17,257]
{
    __shared__ float xl[4352];     // main: 4 slots x 1040; epilogue: 4 x (16x68)
    __shared__ float red[4][16];

    const int fo = blockIdx.x, g = blockIdx.y, b = blockIdx.z;
    const int tid  = threadIdx.x;
    const int lane = tid & 63;
    const int wid  = __builtin_amdgcn_readfirstlane(tid >> 6);
    const int cc = lane & 15;          // fragment column (t or n)
    const int q  = lane >> 4;          // k-group 0..3

    int fvals[2]; int nf = 0;
    if (2*fo - 1 >= 0) fvals[nf++] = 2*fo - 1;
    if (2*fo < 32)     fvals[nf++] = 2*fo;
    const int f0 = fvals[0];
    const int f1 = (nf > 1) ? fvals[1] : f0;

    const int BG = b*128 + g*16;
    const int wlc = (g*16 + cc)*8192 + (q>>1)*512 + 8*(q&1);  // weight lane base
    // LDS read base (floats, without buffer select): slot(q>>1) + pad8 + tau0
    // slot float idx = 8 + tau0 = 64T + 4cc + 8(q&1), T = 4*wid + tt
    const int rbase = (q>>1)*1040 + 4*cc + 8*(q&1) + 256*wid;

    // ---- staging: slice (f,d) -> slot (256 thr x 16B = 4KB interior) ----
    auto stage = [&](int f, int d, int slot) {
        const float* src = x + ((size_t)((BG + d)*32 + f))*1024 + tid*4;
        __builtin_amdgcn_global_load_lds(
            (const __attribute__((address_space(1))) void*)src,
            (__attribute__((address_space(3))) void*)&xl[slot*1040 + 8 + tid*4],
            16, 0, 0);
    };

    // prologue: stage f0 d-pair 0 into buf0 (slots 0,1); zero all pads
    stage(f0, 0, 0);
    stage(f0, 1, 1);
    if (tid < 64) {
        const int slot = tid >> 4, p = tid & 15;
        xl[slot*1040 + (p < 8 ? p : 1024 + p)] = 0.f;
    }

    f32x4 acc[4];
    #pragma unroll
    for (int t = 0; t < 4; ++t) acc[t] = (f32x4){0.f, 0.f, 0.f, 0.f};

    __syncthreads();   // drains prologue stage + publishes pads

    for (int s = 0; s < nf; ++s) {
        const int f = (s == 0) ? f0 : f1;

        // ---- A-frags for this f: 8 d-pairs (L1/L2-resident weights) ----
        short8v afr[8];
        #pragma unroll
        for (int dp = 0; dp < 8; ++dp) {
            const float* wp = wt + wlc + dp*1024 + f*16;
            const float4 w0 = *(const float4*)wp;
            const float4 w1 = *(const float4*)(wp + 4);
            union { short8v s8; short h[8]; } u;
            u.h[0]=f2bf(w0.x); u.h[1]=f2bf(w0.y); u.h[2]=f2bf(w0.z); u.h[3]=f2bf(w0.w);
            u.h[4]=f2bf(w1.x); u.h[5]=f2bf(w1.y); u.h[6]=f2bf(w1.z); u.h[7]=f2bf(w1.w);
            afr[dp] = u.s8;
        }

        #pragma unroll
        for (int dp = 0; dp < 8; ++dp) {
            const int bi = dp & 1;                 // current buffer
            // stage next d-pair into other buffer
            if (!(dp == 7 && s == nf - 1)) {
                const int sn = (dp == 7) ? s + 1 : s;
                const int fn = (sn == 0) ? f0 : f1;
                const int dn = (dp == 7) ? 0 : dp + 1;
                stage(fn, 2*dn,     (bi^1)*2);
                stage(fn, 2*dn + 1, (bi^1)*2 + 1);
            }

            const float* xp = xl + bi*2080 + rbase;
            #pragma unroll
            for (int tt = 0; tt < 4; ++tt) {
                const float4 a0 = *(const float4*)(xp + 64*tt);
                const float4 a1 = *(const float4*)(xp + 64*tt + 4);
                union { short8v s8; short h[8]; } ub;
                ub.h[0]=f2bf(a0.x); ub.h[1]=f2bf(a0.y); ub.h[2]=f2bf(a0.z); ub.h[3]=f2bf(a0.w);
                ub.h[4]=f2bf(a1.x); ub.h[5]=f2bf(a1.y); ub.h[6]=f2bf(a1.z); ub.h[7]=f2bf(a1.w);
                acc[tt] = __builtin_amdgcn_mfma_f32_16x16x32_bf16(
                              afr[dp], ub.s8, acc[tt], 0, 0, 0);
            }
            __syncthreads();   // drain stage(next) + protect rotation
        }
    }

    // ---- epilogue: per-wave transpose tile [16n][68] then coalesced store ----
    {
        float* tp = xl + wid*1088;
        #pragma unroll
        for (int tt = 0; tt < 4; ++tt)
            #pragma unroll
            for (int r = 0; r < 4; ++r) {
                float v = acc[tt][r];
                v = (v > 0.f) ? v : 0.01f*v;
                tp[(q*4 + r)*68 + tt*16 + cc] = v;   // row n=4q+r, col t-16*wid*? (local t)
            }
        #pragma unroll
        for (int p = 0; p < 4; ++p) {
            const int linear = p*64 + lane;
            const int nn = linear >> 4;          // 0..15
            const int c4 = linear & 15;          // 16B chunk of local t
            const float4 vv = *(const float4*)(tp + nn*68 + c4*4);
            const size_t ob = (size_t)(BG + nn)*4369 + (size_t)fo*257
                            + wid*64 + c4*4;
            out[ob + 0] = vv.x; out[ob + 1] = vv.y;
            out[ob + 2] = vv.z; out[ob + 3] = vv.w;
        }
    }

    // ---- t = 256 edge column, fp32 (window taps w=0..7 only) ----
    {
        const int n = tid & 15;
        const int d = tid >> 4;
        const size_t xrow_bg = (size_t)BG * 32768;
        float p = 0.f;
        for (int s = 0; s < nf; ++s) {
            const int f = (s == 0) ? f0 : f1;
            const float* xr = x + xrow_bg + (size_t)d*32768 + (size_t)f*1024 + 1016;
            const float* wr = wt + (size_t)(g*16 + n)*8192 + (size_t)d*512 + f*16;
            #pragma unroll
            for (int w = 0; w < 8; ++w) p = fmaf(xr[w], wr[w], p);
        }
        p += __shfl_xor(p, 16);
        p += __shfl_xor(p, 32);
        if (lane < 16) red[wid][lane] = p;
        __syncthreads();
        if (tid < 16) {
            float v = red[0][tid] + red[1][tid] + red[2][tid] + red[3][tid];
            v = (v > 0.f) ? v : 0.01f*v;
            out[(size_t)(BG + tid)*4369 + (size_t)fo*257 + 256] = v;
        }
    }
}

extern "C" void kernel_launch(void* const* d_in, const int* in_sizes, int n_in,
                              void* d_out, int out_size, void* d_ws, size_t ws_size,
                              hipStream_t stream) {
    const float* x  = (const float*)d_in[0];
    const float* wt = (const float*)d_in[1];
    float* out      = (float*)d_out;
    dim3 grid(17, 8, 8);   // (fo, g, b)
    lconv5<<<grid, TPB, 0, stream>>>(x, wt, out);
}